// Round 5
// baseline (172.287 us; speedup 1.0000x reference)
//
#include <hip/hip_runtime.h>
#include <hip/hip_cooperative_groups.h>

namespace cg = cooperative_groups;

#define HH 512
#define WW 512
#define NB 8
#define NC 128
#define TS 64                 // 64x64 tile
#define NTILES 64             // 8x8 tiles per sample
#define NBLK (NB * NTILES)    // 512 blocks x 512 thr = 4096 waves, 2 blk/CU
#define CUT 9.0f              // exp(-9) ~ 1.2e-4 << 2e-2 tolerance

// R9: R4 (82.7us) + single cooperative launch. The separate reduce kernel
// existed only to sum 512 float2 -- its launch latency + inter-dispatch gap
// was the largest remaining controllable cost (~2-4us). Now: partials via
// agent-scope atomic store (per-XCD L2 non-coherence -- explicit, not via
// CG fence details), grid.sync(), block 0 reduces in-kernel. Bundled free
// micro: CUT 30->9 (error bound 1.2e-4, splat iters -30%).

union f2u { float2 f; unsigned long long u; };

__global__ __launch_bounds__(512) void ahl_main_kernel(
    const float* __restrict__ pred_hm,
    const float* __restrict__ pred_sm,
    const float* __restrict__ mask,
    const float* __restrict__ ground_res,
    const int*   __restrict__ centers,
    float* __restrict__ out,            // out[0]=sl, out[1]=hl, gts at out+2
    float2* __restrict__ partials) {
    __shared__ float4 sc[NC];
    __shared__ int s_cnt;
    __shared__ float redS[8];
    __shared__ float redH[8];

    const int b    = blockIdx.x >> 6;          // / NTILES
    const int tile = blockIdx.x & 63;
    const int tx0  = (tile & 7) * TS;
    const int ty0  = (tile >> 3) * TS;
    const int tid  = threadIdx.x;

    // thread -> 2 rows x 4 consecutive cols (rows ya and ya+32)
    const int cg_  = tid & 15;                 // col group (x4 px)
    const int r0   = tid >> 4;                 // 0..31
    const int x0   = tx0 + cg_ * 4;
    const int ya   = ty0 + r0;
    const int yb   = ya + 32;

    // ---- prefetch epilogue data NOW; latency overlaps prologue + splat
    const size_t sbase = (size_t)b * (HH * WW);
    const size_t ia    = sbase + (size_t)ya * WW + x0;
    const size_t ib    = sbase + (size_t)yb * WW + x0;
    float4 hmA = *(const float4*)&pred_hm[ia];
    float4 smA = *(const float4*)&pred_sm[ia];
    float4 mkA = *(const float4*)&mask[ia];
    float4 hmB = *(const float4*)&pred_hm[ib];
    float4 smB = *(const float4*)&pred_sm[ib];
    float4 mkB = *(const float4*)&mask[ib];

    // ---- fused prologue: wave 0 computes, culls, ballot-compacts 128 centers
    if (tid < 64) {
        const int lane = tid;
        const unsigned long long below = (1ull << lane) - 1ull;
        const float g    = ground_res[b];
        const float base = 0.2f / g;

        // center pair: lane and lane+64
        int2 c0 = *(const int2*)&centers[(b * NC + lane) * 2];
        int2 c1 = *(const int2*)&centers[(b * NC + lane + 64) * 2];

        float4 P0, P1;
        bool k0, k1;
        {
            int cy = min(max(c0.x, 0), HH - 1);
            int cx = min(max(c0.y, 0), WW - 1);
            float smv  = pred_sm[sbase + (size_t)cy * WW + cx];
            float size = base * (1.0f + fmaxf(smv, 0.0f));
            float s    = 0.70710678f / size;   // sqrt(1/(2 size^2))
            P0 = make_float4(s, -(float)cx * s, -(float)cy * s, 0.0f);
            float a0 = fmaf((float)tx0,            P0.x, P0.y);
            float a1 = fmaf((float)(tx0 + TS - 1), P0.x, P0.y);
            float b0 = fmaf((float)ty0,            P0.x, P0.z);
            float b1 = fmaf((float)(ty0 + TS - 1), P0.x, P0.z);
            float dx = fmaxf(0.0f, fmaxf(a0, -a1));
            float dy = fmaxf(0.0f, fmaxf(b0, -b1));
            k0 = fmaf(dx, dx, dy * dy) < CUT;
        }
        {
            int cy = min(max(c1.x, 0), HH - 1);
            int cx = min(max(c1.y, 0), WW - 1);
            float smv  = pred_sm[sbase + (size_t)cy * WW + cx];
            float size = base * (1.0f + fmaxf(smv, 0.0f));
            float s    = 0.70710678f / size;
            P1 = make_float4(s, -(float)cx * s, -(float)cy * s, 0.0f);
            float a0 = fmaf((float)tx0,            P1.x, P1.y);
            float a1 = fmaf((float)(tx0 + TS - 1), P1.x, P1.y);
            float b0 = fmaf((float)ty0,            P1.x, P1.z);
            float b1 = fmaf((float)(ty0 + TS - 1), P1.x, P1.z);
            float dx = fmaxf(0.0f, fmaxf(a0, -a1));
            float dy = fmaxf(0.0f, fmaxf(b0, -b1));
            k1 = fmaf(dx, dx, dy * dy) < CUT;
        }

        unsigned long long m0 = __ballot(k0);
        if (k0) sc[__popcll(m0 & below)] = P0;
        int base1 = __popcll(m0);
        unsigned long long m1 = __ballot(k1);
        if (k1) sc[base1 + __popcll(m1 & below)] = P1;
        if (lane == 0) s_cnt = base1 + __popcll(m1);
    }
    __syncthreads();
    const int cnt = s_cnt;

    // ---- splat: min over culled centers; column term shared across rows
    const float yfa = (float)ya;
    const float yfb = (float)yb;
    float xf[4];
#pragma unroll
    for (int j = 0; j < 4; j++) xf[j] = (float)(x0 + j);
    float mA[4] = {1e30f, 1e30f, 1e30f, 1e30f};
    float mB[4] = {1e30f, 1e30f, 1e30f, 1e30f};

    for (int i = 0; i < cnt; i++) {
        float4 P = sc[i];
        float da = fmaf(yfa, P.x, P.z); da *= da;
        float db = fmaf(yfb, P.x, P.z); db *= db;
#pragma unroll
        for (int j = 0; j < 4; j++) {
            float d  = fmaf(xf[j], P.x, P.y);
            float dd = d * d;
            mA[j] = fminf(mA[j], dd + da);
            mB[j] = fminf(mB[j], dd + db);
        }
    }

    // ---- epilogue (data already in registers)
    float gA0 = __expf(-mA[0]), gA1 = __expf(-mA[1]);
    float gA2 = __expf(-mA[2]), gA3 = __expf(-mA[3]);
    float gB0 = __expf(-mB[0]), gB1 = __expf(-mB[1]);
    float gB2 = __expf(-mB[2]), gB3 = __expf(-mB[3]);

    float2* gpA = (float2*)&out[2 + ia];       // 8B-aligned (ia % 4 == 0)
    gpA[0] = make_float2(gA0, gA1);
    gpA[1] = make_float2(gA2, gA3);
    float2* gpB = (float2*)&out[2 + ib];
    gpB[0] = make_float2(gB0, gB1);
    gpB[1] = make_float2(gB2, gB3);

    float d0 = hmA.x - gA0, d1 = hmA.y - gA1, d2 = hmA.z - gA2, d3 = hmA.w - gA3;
    float lhm = d0 * d0 * mkA.x;
    lhm = fmaf(d1 * d1, mkA.y, lhm);
    lhm = fmaf(d2 * d2, mkA.z, lhm);
    lhm = fmaf(d3 * d3, mkA.w, lhm);
    d0 = hmB.x - gB0; d1 = hmB.y - gB1; d2 = hmB.z - gB2; d3 = hmB.w - gB3;
    lhm = fmaf(d0 * d0, mkB.x, lhm);
    lhm = fmaf(d1 * d1, mkB.y, lhm);
    lhm = fmaf(d2 * d2, mkB.z, lhm);
    lhm = fmaf(d3 * d3, mkB.w, lhm);

    float lsc = smA.x * smA.x;
    lsc = fmaf(smA.y, smA.y, lsc);
    lsc = fmaf(smA.z, smA.z, lsc);
    lsc = fmaf(smA.w, smA.w, lsc);
    lsc = fmaf(smB.x, smB.x, lsc);
    lsc = fmaf(smB.y, smB.y, lsc);
    lsc = fmaf(smB.z, smB.z, lsc);
    lsc = fmaf(smB.w, smB.w, lsc);

    // block reduction (8 waves)
#pragma unroll
    for (int off = 32; off > 0; off >>= 1) {
        lhm += __shfl_down(lhm, off);
        lsc += __shfl_down(lsc, off);
    }
    int lane = tid & 63, wid = tid >> 6;
    if (lane == 0) { redS[wid] = lsc; redH[wid] = lhm; }
    __syncthreads();
    if (tid == 0) {
        float ts = 0.0f, th = 0.0f;
#pragma unroll
        for (int w = 0; w < 8; w++) { ts += redS[w]; th += redH[w]; }
        f2u v; v.f = make_float2(ts, th);
        // agent-scope store: partials must be visible across XCD L2s
        __hip_atomic_store((unsigned long long*)&partials[blockIdx.x], v.u,
                           __ATOMIC_RELAXED, __HIP_MEMORY_SCOPE_AGENT);
    }

    // ---- grid-wide sync, then block 0 reduces the 512 partials
    cg::this_grid().sync();

    if (blockIdx.x == 0) {
        f2u v;
        v.u = __hip_atomic_load((const unsigned long long*)&partials[tid],
                                __ATOMIC_RELAXED, __HIP_MEMORY_SCOPE_AGENT);
        float ts = v.f.x, th = v.f.y;
#pragma unroll
        for (int off = 32; off > 0; off >>= 1) {
            ts += __shfl_down(ts, off);
            th += __shfl_down(th, off);
        }
        if (lane == 0) { redS[wid] = ts; redH[wid] = th; }
        __syncthreads();
        if (tid == 0) {
            const float invc = 1.0f / (float)((size_t)NB * HH * WW);
            float s0 = 0.0f, h0 = 0.0f;
#pragma unroll
            for (int w = 0; w < 8; w++) { s0 += redS[w]; h0 += redH[w]; }
            out[0] = s0 * invc;
            out[1] = h0 * invc;
        }
    }
}

extern "C" void kernel_launch(void* const* d_in, const int* in_sizes, int n_in,
                              void* d_out, int out_size, void* d_ws, size_t ws_size,
                              hipStream_t stream) {
    const float* pred_hm    = (const float*)d_in[0];
    const float* pred_sm    = (const float*)d_in[1];
    const float* ground_res = (const float*)d_in[2];
    const float* mask       = (const float*)d_in[3];
    const int*   centers    = (const int*)d_in[4];
    float* out = (float*)d_out;
    float2* partials = (float2*)d_ws;   // NBLK float2 = 4 KB

    void* args[] = {(void*)&pred_hm, (void*)&pred_sm, (void*)&mask,
                    (void*)&ground_res, (void*)&centers, (void*)&out,
                    (void*)&partials};
    hipLaunchCooperativeKernel(ahl_main_kernel, dim3(NBLK), dim3(512),
                               args, 0, stream);
}

// Round 6
// 84.927 us; speedup vs baseline: 2.0286x; 2.0286x over previous
//
#include <hip/hip_runtime.h>

#define HH 512
#define WW 512
#define NB 8
#define NC 128
#define TS 64                 // 64x64 tile
#define NTILES 64             // 8x8 tiles per sample
#define NBLK (NB * NTILES)    // 512 blocks x 512 thr = 4096 waves, 2 blk/CU
#define CUT 9.0f              // exp(-9) ~ 1.2e-4 << 2e-2 tol (validated R5)

// R10 = R4 revert (82.7us, best) + validated CUT 30->9 (splat iters -30%).
// R5 lesson: grid.sync() on 512 blocks costs ~70us (cross-XCD device-scope
// spin) -- fusion via cooperative launch is strictly worse than the 2nd
// launch. No zero-init word exists for a last-block trick (ws re-poisoned
// every iter), so the 2-kernel structure stands. R5 also showed inputs are
// L3-resident (FETCH 12.9MB < 33.6MB inputs): main kernel is near its
// small L3-fed floor; remaining window is harness fill (~45us @ fill
// ceiling) + reset/launch machinery.

__global__ __launch_bounds__(512) void ahl_main_kernel(
    const float* __restrict__ pred_hm,
    const float* __restrict__ pred_sm,
    const float* __restrict__ mask,
    const float* __restrict__ ground_res,
    const int*   __restrict__ centers,
    float* __restrict__ out,            // out[0]=sl, out[1]=hl, gts at out+2
    float2* __restrict__ partials) {
    __shared__ float4 sc[NC];
    __shared__ int s_cnt;
    __shared__ float redS[8];
    __shared__ float redH[8];

    const int b    = blockIdx.x >> 6;          // / NTILES
    const int tile = blockIdx.x & 63;
    const int tx0  = (tile & 7) * TS;
    const int ty0  = (tile >> 3) * TS;
    const int tid  = threadIdx.x;

    // thread -> 2 rows x 4 consecutive cols (rows ya and ya+32)
    const int cg  = tid & 15;                  // col group (x4 px)
    const int r0  = tid >> 4;                  // 0..31
    const int x0  = tx0 + cg * 4;
    const int ya  = ty0 + r0;
    const int yb  = ya + 32;

    // ---- prefetch epilogue data NOW; latency overlaps prologue + splat
    const size_t sbase = (size_t)b * (HH * WW);
    const size_t ia    = sbase + (size_t)ya * WW + x0;
    const size_t ib    = sbase + (size_t)yb * WW + x0;
    float4 hmA = *(const float4*)&pred_hm[ia];
    float4 smA = *(const float4*)&pred_sm[ia];
    float4 mkA = *(const float4*)&mask[ia];
    float4 hmB = *(const float4*)&pred_hm[ib];
    float4 smB = *(const float4*)&pred_sm[ib];
    float4 mkB = *(const float4*)&mask[ib];

    // ---- fused prologue: wave 0 computes, culls, ballot-compacts 128 centers
    if (tid < 64) {
        const int lane = tid;
        const unsigned long long below = (1ull << lane) - 1ull;
        const float g    = ground_res[b];
        const float base = 0.2f / g;

        // center pair: lane and lane+64
        int2 c0 = *(const int2*)&centers[(b * NC + lane) * 2];
        int2 c1 = *(const int2*)&centers[(b * NC + lane + 64) * 2];

        float4 P0, P1;
        bool k0, k1;
        {
            int cy = min(max(c0.x, 0), HH - 1);
            int cx = min(max(c0.y, 0), WW - 1);
            float smv  = pred_sm[sbase + (size_t)cy * WW + cx];
            float size = base * (1.0f + fmaxf(smv, 0.0f));
            float s    = 0.70710678f / size;   // sqrt(1/(2 size^2))
            P0 = make_float4(s, -(float)cx * s, -(float)cy * s, 0.0f);
            float a0 = fmaf((float)tx0,            P0.x, P0.y);
            float a1 = fmaf((float)(tx0 + TS - 1), P0.x, P0.y);
            float b0 = fmaf((float)ty0,            P0.x, P0.z);
            float b1 = fmaf((float)(ty0 + TS - 1), P0.x, P0.z);
            float dx = fmaxf(0.0f, fmaxf(a0, -a1));
            float dy = fmaxf(0.0f, fmaxf(b0, -b1));
            k0 = fmaf(dx, dx, dy * dy) < CUT;
        }
        {
            int cy = min(max(c1.x, 0), HH - 1);
            int cx = min(max(c1.y, 0), WW - 1);
            float smv  = pred_sm[sbase + (size_t)cy * WW + cx];
            float size = base * (1.0f + fmaxf(smv, 0.0f));
            float s    = 0.70710678f / size;
            P1 = make_float4(s, -(float)cx * s, -(float)cy * s, 0.0f);
            float a0 = fmaf((float)tx0,            P1.x, P1.y);
            float a1 = fmaf((float)(tx0 + TS - 1), P1.x, P1.y);
            float b0 = fmaf((float)ty0,            P1.x, P1.z);
            float b1 = fmaf((float)(ty0 + TS - 1), P1.x, P1.z);
            float dx = fmaxf(0.0f, fmaxf(a0, -a1));
            float dy = fmaxf(0.0f, fmaxf(b0, -b1));
            k1 = fmaf(dx, dx, dy * dy) < CUT;
        }

        unsigned long long m0 = __ballot(k0);
        if (k0) sc[__popcll(m0 & below)] = P0;
        int base1 = __popcll(m0);
        unsigned long long m1 = __ballot(k1);
        if (k1) sc[base1 + __popcll(m1 & below)] = P1;
        if (lane == 0) s_cnt = base1 + __popcll(m1);
    }
    __syncthreads();
    const int cnt = s_cnt;

    // ---- splat: min over culled centers; column term shared across rows
    const float yfa = (float)ya;
    const float yfb = (float)yb;
    float xf[4];
#pragma unroll
    for (int j = 0; j < 4; j++) xf[j] = (float)(x0 + j);
    float mA[4] = {1e30f, 1e30f, 1e30f, 1e30f};
    float mB[4] = {1e30f, 1e30f, 1e30f, 1e30f};

    for (int i = 0; i < cnt; i++) {
        float4 P = sc[i];
        float da = fmaf(yfa, P.x, P.z); da *= da;
        float db = fmaf(yfb, P.x, P.z); db *= db;
#pragma unroll
        for (int j = 0; j < 4; j++) {
            float d  = fmaf(xf[j], P.x, P.y);
            float dd = d * d;
            mA[j] = fminf(mA[j], dd + da);
            mB[j] = fminf(mB[j], dd + db);
        }
    }

    // ---- epilogue (data already in registers)
    float gA0 = __expf(-mA[0]), gA1 = __expf(-mA[1]);
    float gA2 = __expf(-mA[2]), gA3 = __expf(-mA[3]);
    float gB0 = __expf(-mB[0]), gB1 = __expf(-mB[1]);
    float gB2 = __expf(-mB[2]), gB3 = __expf(-mB[3]);

    float2* gpA = (float2*)&out[2 + ia];       // 8B-aligned (ia % 4 == 0)
    gpA[0] = make_float2(gA0, gA1);
    gpA[1] = make_float2(gA2, gA3);
    float2* gpB = (float2*)&out[2 + ib];
    gpB[0] = make_float2(gB0, gB1);
    gpB[1] = make_float2(gB2, gB3);

    float d0 = hmA.x - gA0, d1 = hmA.y - gA1, d2 = hmA.z - gA2, d3 = hmA.w - gA3;
    float lhm = d0 * d0 * mkA.x;
    lhm = fmaf(d1 * d1, mkA.y, lhm);
    lhm = fmaf(d2 * d2, mkA.z, lhm);
    lhm = fmaf(d3 * d3, mkA.w, lhm);
    d0 = hmB.x - gB0; d1 = hmB.y - gB1; d2 = hmB.z - gB2; d3 = hmB.w - gB3;
    lhm = fmaf(d0 * d0, mkB.x, lhm);
    lhm = fmaf(d1 * d1, mkB.y, lhm);
    lhm = fmaf(d2 * d2, mkB.z, lhm);
    lhm = fmaf(d3 * d3, mkB.w, lhm);

    float lsc = smA.x * smA.x;
    lsc = fmaf(smA.y, smA.y, lsc);
    lsc = fmaf(smA.z, smA.z, lsc);
    lsc = fmaf(smA.w, smA.w, lsc);
    lsc = fmaf(smB.x, smB.x, lsc);
    lsc = fmaf(smB.y, smB.y, lsc);
    lsc = fmaf(smB.z, smB.z, lsc);
    lsc = fmaf(smB.w, smB.w, lsc);

    // block reduction (8 waves)
#pragma unroll
    for (int off = 32; off > 0; off >>= 1) {
        lhm += __shfl_down(lhm, off);
        lsc += __shfl_down(lsc, off);
    }
    int lane = tid & 63, wid = tid >> 6;
    if (lane == 0) { redS[wid] = lsc; redH[wid] = lhm; }
    __syncthreads();
    if (tid == 0) {
        float ts = 0.0f, th = 0.0f;
#pragma unroll
        for (int w = 0; w < 8; w++) { ts += redS[w]; th += redH[w]; }
        partials[blockIdx.x] = make_float2(ts, th);   // plain store; kernel
    }                                                  // boundary orders it
}

__global__ __launch_bounds__(256) void ahl_reduce_kernel(
    const float2* __restrict__ partials, float* __restrict__ out) {
    __shared__ float red[8];
    const int tid = threadIdx.x;
    float ts = 0.0f, th = 0.0f;
    for (int s = tid; s < NBLK; s += 256) {    // 2 slots per thread
        float2 a = partials[s];
        ts += a.x;
        th += a.y;
    }
#pragma unroll
    for (int off = 32; off > 0; off >>= 1) {
        ts += __shfl_down(ts, off);
        th += __shfl_down(th, off);
    }
    int lane = tid & 63, wid = tid >> 6;
    if (lane == 0) { red[wid] = ts; red[4 + wid] = th; }
    __syncthreads();
    if (tid == 0) {
        const float invc = 1.0f / (float)((size_t)NB * HH * WW);
        out[0] = (red[0] + red[1] + red[2] + red[3]) * invc;
        out[1] = (red[4] + red[5] + red[6] + red[7]) * invc;
    }
}

extern "C" void kernel_launch(void* const* d_in, const int* in_sizes, int n_in,
                              void* d_out, int out_size, void* d_ws, size_t ws_size,
                              hipStream_t stream) {
    const float* pred_hm    = (const float*)d_in[0];
    const float* pred_sm    = (const float*)d_in[1];
    const float* ground_res = (const float*)d_in[2];
    const float* mask       = (const float*)d_in[3];
    const int*   centers    = (const int*)d_in[4];
    float* out = (float*)d_out;
    float2* partials = (float2*)d_ws;   // NBLK float2 = 4 KB

    ahl_main_kernel<<<NBLK, 512, 0, stream>>>(pred_hm, pred_sm, mask,
                                              ground_res, centers, out,
                                              partials);
    ahl_reduce_kernel<<<1, 256, 0, stream>>>(partials, out);
}